// Round 12
// baseline (8847.273 us; speedup 1.0000x reference)
//
#include <hip/hip_runtime.h>
#include <hip/hip_cooperative_groups.h>

#define B 256
#define T 2048
#define HDIM 128
#define CH 128
#define NCHUNK (T / CH)

typedef _Float16 f16;
typedef _Float16 h2 __attribute__((ext_vector_type(2)));
typedef _Float16 f16x8 __attribute__((ext_vector_type(8)));
typedef float f32x4 __attribute__((ext_vector_type(4)));

__device__ __forceinline__ float dot2(h2 a, h2 b, float c) {
#if __has_builtin(__builtin_amdgcn_fdot2)
    return __builtin_amdgcn_fdot2(a, b, c, false);
#else
    return c + (float)a[0] * (float)b[0] + (float)a[1] * (float)b[1];
#endif
}

__device__ __forceinline__ float rcp_(float x) {
#if __has_builtin(__builtin_amdgcn_rcpf)
    return __builtin_amdgcn_rcpf(x);
#else
    return 1.0f / x;
#endif
}
// approx activations via v_rcp (~1e-6 rel err; threshold is 1e-2)
__device__ __forceinline__ float sigm(float x) { return rcp_(1.0f + __expf(-x)); }
// tanh(x) = 2*sigm(2x)-1; saturates correctly at +/-inf (r8-proven)
__device__ __forceinline__ float tanh2(float x) {
    return fmaf(2.0f, rcp_(1.0f + __expf(-2.0f * x)), -1.0f);
}

// quad-perm exchanges via DPP (pure VALU) -- r11-proven vs ds_bpermute
__device__ __forceinline__ float dpp_x1(float x) {
#if __has_builtin(__builtin_amdgcn_update_dpp)
    union { float f; int i; } u, r;
    u.f = x;
    r.i = __builtin_amdgcn_update_dpp(0, u.i, 0xB1, 0xF, 0xF, true);
    return r.f;
#else
    return __shfl_xor(x, 1);
#endif
}
__device__ __forceinline__ float dpp_x2(float x) {
#if __has_builtin(__builtin_amdgcn_update_dpp)
    union { float f; int i; } u, r;
    u.f = x;
    r.i = __builtin_amdgcn_update_dpp(0, u.i, 0x4E, 0xF, 0xF, true);
    return r.f;
#else
    return __shfl_xor(x, 2);
#endif
}

__device__ __forceinline__ void bar() {
    // LDS-only barrier: order ds ops, do NOT drain vmcnt
    asm volatile("s_waitcnt lgkmcnt(0)" ::: "memory");
    __builtin_amdgcn_s_barrier();
}

// ---------------- fc1: scent[B,T,3] -> x1[T,B,32] f16 (24 real + 8 zero pad) ---------
__global__ __launch_bounds__(256) void fc1_kernel(
    const float* __restrict__ scent,
    const float* __restrict__ W1, const float* __restrict__ b1,
    const float* __restrict__ W2, const float* __restrict__ b2,
    f16* __restrict__ x1) {
    int r = blockIdx.x * 256 + threadIdx.x;   // r = b*T + t
    int b = r >> 11, t = r & 2047;
    float s0 = scent[r * 3], s1 = scent[r * 3 + 1], s2 = scent[r * 3 + 2];
    float a[12];
#pragma unroll
    for (int i = 0; i < 12; i++) {
        float v = W1[i * 3] * s0 + W1[i * 3 + 1] * s1 + W1[i * 3 + 2] * s2 + b1[i];
        a[i] = fmaxf(v, 0.f);
    }
    union { f16 o[32]; uint4 u[4]; } U;
#pragma unroll
    for (int j = 0; j < 24; j++) {
        float v = b2[j];
#pragma unroll
        for (int i = 0; i < 12; i++) v = fmaf(W2[j * 12 + i], a[i], v);
        U.o[j] = (f16)fmaxf(v, 0.f);
    }
#pragma unroll
    for (int j = 24; j < 32; j++) U.o[j] = (f16)0.f;
    uint4* d4 = (uint4*)(x1 + ((size_t)t * B + b) * 32);
#pragma unroll
    for (int i = 0; i < 4; i++) d4[i] = U.u[i];
}

// ---------------- pack Wf1 f32 -> half2 ----------------
__global__ __launch_bounds__(256) void pack_kernel(const float* __restrict__ w,
                                                   unsigned int* __restrict__ o) {
    int i = blockIdx.x * 256 + threadIdx.x;
    if (i < 4096) {
        union { h2 h; unsigned int u; } U;
        U.h[0] = (f16)w[2 * i];
        U.h[1] = (f16)w[2 * i + 1];
        o[i] = U.u;
    }
}

// ---------------- persistent cooperative LSTM layer ----------------
// 256 blocks x 512 thr (8 waves = 2/SIMD everywhere; co-resident by design).
// Per chunk (CH=128, gx double-buffered in ws):
//   GEMM phase: wave (bb*8+wv) owns 16 rows of the next chunk; A-frags in regs,
//     stream 32 gate-tiles x KF MFMA (Wih from L2/L3), write gx+biases.
//   grid.sync
//   REC phase: r11 quad shape (j=tid>>2, q=tid&3): 64 dot2, DPP quad butterfly,
//     in-register cell update, ONE bar/step; gx via monotone-pointer ring
//     (refills peeled 8 steps early -> no buffer overrun).
//   grid.sync
// Weights load once per layer; no hS/cS round-trips; 1 launch per layer.
template <int KF, int KREAL>
__global__ __attribute__((amdgpu_flat_work_group_size(512, 512), amdgpu_waves_per_eu(2, 2)))
void lstm_layer(
    const f16* x,                    // [T][B][KIN], KIN=KF*32 (may alias y)
    const float* __restrict__ Wih,   // [512][KREAL]
    const float* __restrict__ Whh,   // [512][128]
    const float* __restrict__ bih, const float* __restrict__ bhh,
    f16* y,                          // [T][B][128]
    float* __restrict__ hT, float* __restrict__ cT,   // [B][128]
    f16* __restrict__ gxA, f16* __restrict__ gxB) {   // 2 x [CH*B][512]
    constexpr int KIN = KF * 32;
    cooperative_groups::grid_group grid = cooperative_groups::this_grid();
    __shared__ __align__(16) f16 hbuf[2][HDIM];

    const int tid = threadIdx.x, bb = blockIdx.x;
    const int j = tid >> 2, q = tid & 3;
    const int wv = tid >> 6, l = tid & 63;
    const int lc = l & 15, lg = l >> 4;
    const int wid = bb * 8 + wv;     // global wave id: owns rows [wid*16, wid*16+16)

    // ---- rec weights: gates {j,128+j,256+j,384+j}, k in [32q,32q+32) ----
    h2 wh[4][16];
#pragma unroll
    for (int gi = 0; gi < 4; gi++) {
        const float* wr = Whh + (size_t)(gi * 128 + j) * HDIM + 32 * q;
#pragma unroll
        for (int kk = 0; kk < 16; kk++) {
            h2 p; p[0] = (f16)wr[2 * kk]; p[1] = (f16)wr[2 * kk + 1];
            wh[gi][kk] = p;
        }
    }
    float c = 0.f, hh = 0.f;
    if (q == 0) hbuf[0][j] = (f16)0.f;

    f16* gxbuf0 = gxA;
    f16* gxbuf1 = gxB;

    // ---- gemm for chunk ch -> gxbuf[ch&1] ----
    auto do_gemm = [&](int ch) {
        f16* gxo = ((ch & 1) ? gxbuf1 : gxbuf0) + (size_t)wid * 16 * 512;
        const size_t rowbase = (size_t)ch * CH * B + (size_t)wid * 16;
        f16x8 af[KF];
#pragma unroll
        for (int kf = 0; kf < KF; kf++)
            af[kf] = *(const f16x8*)(x + (rowbase + lc) * KIN + kf * 32 + lg * 8);
        for (int gt = 0; gt < 32; gt++) {
            int g = gt * 16 + lc;
            float bs = bih[g] + bhh[g];
            f32x4 a = {bs, bs, bs, bs};
#pragma unroll
            for (int kf = 0; kf < KF; kf++) {
                const float* wr = Wih + (size_t)g * KREAL + kf * 32 + lg * 8;
                f16x8 bf;
#pragma unroll
                for (int e = 0; e < 8; e++) {
                    int k = kf * 32 + lg * 8 + e;
                    bf[e] = (k < KREAL) ? (f16)wr[e] : (f16)0.f;
                }
                a = __builtin_amdgcn_mfma_f32_16x16x32_f16(af[kf], bf, a, 0, 0, 0);
            }
#pragma unroll
            for (int qq = 0; qq < 4; qq++)
                gxo[(size_t)(4 * lg + qq) * 512 + g] = (f16)a[qq];
        }
    };

    do_gemm(0);
    grid.sync();

#define RSTEP(TT, JJ, RF)                                                      \
    {                                                                           \
        const int p_ = (TT) & 1;                                                \
        union { ushort u; f16 h; } GU_; GU_.u = gxr[JJ];                        \
        float gxv = (float)GU_.h;                                               \
        if (RF) { gxr[JJ] = *gq; gq += B * 512; }                               \
        union { uint4 u[4]; h2 h[16]; } S_;                                     \
        {                                                                       \
            const uint4* kp = (const uint4*)(&hbuf[p_][32 * q]);                \
            S_.u[0] = kp[0]; S_.u[1] = kp[1]; S_.u[2] = kp[2]; S_.u[3] = kp[3]; \
        }                                                                       \
        float a0 = (q == 0) ? gxv : 0.f, a1 = (q == 1) ? gxv : 0.f;             \
        float a2 = (q == 2) ? gxv : 0.f, a3 = (q == 3) ? gxv : 0.f;             \
        _Pragma("unroll")                                                       \
        for (int kk = 0; kk < 16; kk++) {                                       \
            a0 = dot2(wh[0][kk], S_.h[kk], a0);                                 \
            a1 = dot2(wh[1][kk], S_.h[kk], a1);                                 \
            a2 = dot2(wh[2][kk], S_.h[kk], a2);                                 \
            a3 = dot2(wh[3][kk], S_.h[kk], a3);                                 \
        }                                                                       \
        a0 += dpp_x1(a0); a1 += dpp_x1(a1); a2 += dpp_x1(a2); a3 += dpp_x1(a3); \
        a0 += dpp_x2(a0); a1 += dpp_x2(a1); a2 += dpp_x2(a2); a3 += dpp_x2(a3); \
        float gi_ = sigm(a0), gf_ = sigm(a1), gg_ = tanh2(a2), go_ = sigm(a3);  \
        c = gf_ * c + gi_ * gg_;                                                \
        hh = go_ * tanh2(c);                                                    \
        if (q == 0) { hbuf[p_ ^ 1][j] = (f16)hh; *yp = (f16)hh; }               \
        yp += (size_t)B * HDIM;                                                 \
        bar();                                                                  \
    }

    for (int ch = 0; ch < NCHUNK; ch++) {
        // ---- REC phase: 128 steps for row bb ----
        const f16* gxc = (ch & 1) ? gxbuf1 : gxbuf0;
        const ushort* gp = (const ushort*)gxc + (size_t)bb * 512 + q * 128 + j;
        ushort gxr[8];
#pragma unroll
        for (int jj = 0; jj < 8; jj++) gxr[jj] = gp[(size_t)jj * (B * 512)];
        const ushort* gq = gp + (size_t)8 * (B * 512);
        f16* yp = y + ((size_t)ch * CH * B + bb) * HDIM + j;

        for (int w8 = 0; w8 < CH / 8 - 1; w8++) {
#pragma unroll
            for (int jj = 0; jj < 8; jj++) RSTEP(w8 * 8 + jj, jj, 1)
        }
#pragma unroll
        for (int jj = 0; jj < 8; jj++) RSTEP(CH - 8 + jj, jj, 0)

        grid.sync();
        if (ch + 1 < NCHUNK) {
            do_gemm(ch + 1);
            grid.sync();
        }
    }
#undef RSTEP

    if (q == 0) {
        hT[(size_t)bb * HDIM + j] = hh;
        cT[(size_t)bb * HDIM + j] = c;
    }
}

// ---------------- fc2: y[T,B,128] f16 -> out[B,T,32] f32 ----------------
__global__ __launch_bounds__(256) void fc2_kernel(
    const f16* __restrict__ yin,
    const unsigned int* __restrict__ w1,  // [64][64] half2-packed Wf1
    const float* __restrict__ bf1,
    const float* __restrict__ Wf2,        // [32][64] f32
    const float* __restrict__ bf2,
    float* __restrict__ out) {
    int r = blockIdx.x * 256 + threadIdx.x;   // r = t*B + b
    union { uint4 u4[16]; h2 h[64]; } Y;
    {
        const uint4* yr4 = (const uint4*)(yin + (size_t)r * 128);
#pragma unroll
        for (int i = 0; i < 16; i++) Y.u4[i] = yr4[i];
    }
    float acc2[32];
#pragma unroll
    for (int i = 0; i < 32; i++) acc2[i] = 0.f;

    for (int cO = 0; cO < 64; cO++) {
        float a0 = bf1[cO], a1 = 0.f, a2 = 0.f, a3 = 0.f;
#pragma unroll
        for (int kk = 0; kk < 64; kk += 4) {
            union { unsigned int u; h2 h; } W0, W1x, W2x, W3;
            W0.u = w1[cO * 64 + kk];      a0 = dot2(W0.h,  Y.h[kk],     a0);
            W1x.u = w1[cO * 64 + kk + 1]; a1 = dot2(W1x.h, Y.h[kk + 1], a1);
            W2x.u = w1[cO * 64 + kk + 2]; a2 = dot2(W2x.h, Y.h[kk + 2], a2);
            W3.u = w1[cO * 64 + kk + 3];  a3 = dot2(W3.h,  Y.h[kk + 3], a3);
        }
        float a = fmaxf((a0 + a1) + (a2 + a3), 0.f);
#pragma unroll
        for (int c2 = 0; c2 < 32; c2++) acc2[c2] = fmaf(a, Wf2[c2 * 64 + cO], acc2[c2]);
    }
    float* orow = out + ((size_t)(r & 255) * T + (r >> 8)) * 32;
#pragma unroll
    for (int c2 = 0; c2 < 32; c2++) orow[c2] = fmaxf(acc2[c2] + bf2[c2], 0.f);
}

// ---------------- launch ----------------
extern "C" void kernel_launch(void* const* d_in, const int* in_sizes, int n_in,
                              void* d_out, int out_size, void* d_ws, size_t ws_size,
                              hipStream_t stream) {
    const float* scent = (const float*)d_in[0];
    const float* W1 = (const float*)d_in[1];
    const float* b1 = (const float*)d_in[2];
    const float* W2 = (const float*)d_in[3];
    const float* b2 = (const float*)d_in[4];
    const float* Wih[3] = {(const float*)d_in[5], (const float*)d_in[9], (const float*)d_in[13]};
    const float* Whh[3] = {(const float*)d_in[6], (const float*)d_in[10], (const float*)d_in[14]};
    const float* bihp[3] = {(const float*)d_in[7], (const float*)d_in[11], (const float*)d_in[15]};
    const float* bhhp[3] = {(const float*)d_in[8], (const float*)d_in[12], (const float*)d_in[16]};
    const float* Wf1 = (const float*)d_in[17];
    const float* bf1 = (const float*)d_in[18];
    const float* Wf2 = (const float*)d_in[19];
    const float* bf2 = (const float*)d_in[20];

    const size_t o_x1 = 0;                        // 32 MB: x1 [T,B,32] f16
    const size_t o_y  = 33554432;                 // 128 MB: yb [T,B,128] f16
    const size_t o_w1 = o_y + 134217728;          // 16 KB: packed Wf1
    const size_t o_gx = o_w1 + 16384;             // 64 MB: gx 2 x [CH*B][512] f16
    const size_t need = o_gx + 67108864;
    if (ws_size < need) return;

    char* ws = (char*)d_ws;
    f16* x1 = (f16*)(ws + o_x1);
    f16* yb = (f16*)(ws + o_y);
    unsigned int* w1p = (unsigned int*)(ws + o_w1);
    f16* gx0 = (f16*)(ws + o_gx);
    f16* gx1 = gx0 + (size_t)CH * B * 512;

    float* out = (float*)d_out;
    float* hO = out + (size_t)B * T * 32;
    float* cO = hO + 3 * B * HDIM;

    pack_kernel<<<16, 256, 0, stream>>>(Wf1, w1p);
    fc1_kernel<<<(B * T) / 256, 256, 0, stream>>>(scent, W1, b1, W2, b2, x1);

    // cooperative lstm layers (one launch each)
    {
        void (*k1)(const f16*, const float*, const float*, const float*, const float*,
                   f16*, float*, float*, f16*, f16*) = lstm_layer<1, 24>;
        void (*k4)(const f16*, const float*, const float*, const float*, const float*,
                   f16*, float*, float*, f16*, f16*) = lstm_layer<4, 128>;
        for (int lyr = 0; lyr < 3; lyr++) {
            const f16* xl = (lyr == 0) ? (const f16*)x1 : (const f16*)yb;
            const float* wih = Wih[lyr];
            const float* whh = Whh[lyr];
            const float* bi = bihp[lyr];
            const float* bh = bhhp[lyr];
            f16* yl = yb;
            float* hS = hO + (size_t)lyr * B * HDIM;
            float* cS = cO + (size_t)lyr * B * HDIM;
            f16* g0 = gx0;
            f16* g1 = gx1;
            void* args[] = {(void*)&xl, (void*)&wih, (void*)&whh, (void*)&bi, (void*)&bh,
                            (void*)&yl, (void*)&hS, (void*)&cS, (void*)&g0, (void*)&g1};
            hipLaunchCooperativeKernel((lyr == 0) ? (void*)k1 : (void*)k4,
                                       dim3(B), dim3(512), args, 0, stream);
        }
    }

    fc2_kernel<<<(B * T) / 256, 256, 0, stream>>>(yb, w1p, bf1, Wf2, bf2, out);
}